// Round 13
// baseline (459.457 us; speedup 1.0000x reference)
//
#include <hip/hip_runtime.h>

#define T_LEN 512
#define D_DIM 32
#define N_DIM 64
#define B_ALL 128
#define R_TILE 16     // real batch rows per block == FULL MFMA M (no padding)
#define M_DIM 16      // MFMA M dimension
#define HSTR 72       // ushort row stride for h plane: 16B-aligned, bank-spread

typedef _Float16 h8v __attribute__((ext_vector_type(8)));  // 8 f16 (4 VGPRs)
typedef float f4v __attribute__((ext_vector_type(4)));     // MFMA C/D
typedef unsigned int uint;
typedef unsigned short u16;

__device__ __forceinline__ float rcp_f(float x) {
#if __has_builtin(__builtin_amdgcn_rcpf)
    return __builtin_amdgcn_rcpf(x);
#else
    return 1.0f / x;
#endif
}
__device__ __forceinline__ float tanh_f(float x) {
    float e = __expf(2.0f * x);
    return 1.0f - 2.0f * rcp_f(e + 1.0f);
}
__device__ __forceinline__ float sig_f(float x) {
    return rcp_f(1.0f + __expf(-x));
}
__device__ __forceinline__ uint f2h2(float a, float b) {   // pack two f16 (RNE)
    union { _Float16 h[2]; uint u; } x;
    x.h[0] = (_Float16)a; x.h[1] = (_Float16)b;
    return x.u;
}
__device__ __forceinline__ h8v pack4h(uint a, uint b, uint c, uint d_) {
    union { uint u[4]; h8v v; } x;
    x.u[0] = a; x.u[1] = b; x.u[2] = c; x.u[3] = d_;
    return x.v;
}

// R13 (on R12's f16 single-plane base, 357us dispatch): FULL-M TILE.
// Accounting at R12: VALU 1094cy/SIMD-step (65%, fixed per (row,n) pair),
// MFMA 345cy (21%), stall 236. MFMA was 2x redundant: each wave's 16-row C
// tile had only 8 real rows (M-permutation padding). Now block = (d, 16
// rows), grid 256 = 32d x 8 tiles, 4 waves, 1 block/CU: every lane's 4 C
// regs are 4 REAL rows (quad*4..+3). Per-CU-step: VALU unchanged (same
// 1024 pairs), MFMA HALVES (345 -> ~170cy/SIMD), A-read traffic per pair
// halves. Sum 1439 -> ~1270cy. Risk (R0 lesson): 1 wave/SIMD has no TLP
// stall coverage -- but the loop is far leaner than R0's (no shfl chains,
// no sPS round-trip, 10 MFMAs) and each lane has 4 independent row-chains
// of ILP for the trans unit. Occupancy ~9.7% is EXPECTED, not failure.
// Everything else identical to R12: f16 h plane, MFMA-folded alpha
// (col-replicated fan, as-init cancels the spurious t=-1 term), 1 barrier.
// NOTE: C-fold of x*U+b into MFMA C-in regressed (R5/R6) - keep acc=0.
__global__ void __launch_bounds__(256, 1)
imv_lstm_scan(const float* __restrict__ x,
              const float* __restrict__ Uj, const float* __restrict__ Ui,
              const float* __restrict__ Uf, const float* __restrict__ Uo,
              const float* __restrict__ Wj, const float* __restrict__ Wi,
              const float* __restrict__ Wf, const float* __restrict__ Wo,
              const float* __restrict__ bj, const float* __restrict__ bi_,
              const float* __restrict__ bf_, const float* __restrict__ bo,
              const float* __restrict__ Fa, const float* __restrict__ Fab,
              const float* __restrict__ Fbw, const float* __restrict__ Fbb,
              const float* __restrict__ Pw, const float* __restrict__ Pb,
              float* __restrict__ wmu, float* __restrict__ wbeta)
{
    __shared__ float sXT[T_LEN][R_TILE];     // 32 KB, [t][r]
    __shared__ u16   sHh[2][M_DIM][HSTR];    // 4.5 KB, h f16, [buf][row][k]
    __shared__ float sPS[R_TILE][4];         // epilogue mu partials
    __shared__ float sPV[R_TILE][4];         // epilogue beta partials

    const int tid  = threadIdx.x;
    const int lane = tid & 63;
    const int wg   = tid >> 6;               // 0..3 (n-group)
    const int quad = lane >> 4;              // 0..3
    const int col  = lane & 15;
    const int d    = blockIdx.x & 31;
    const int rt   = blockIdx.x >> 5;        // 0..7
    const int r0   = rt * R_TILE;
    const int n    = wg * 16 + col;          // this lane's n
    const int rrow = quad * 4;               // lane's 4 real rows rrow..+3

    // ---- stage x transposed: sXT[t][r] ----
    for (int i = tid; i < R_TILE * T_LEN; i += 256) {
        int t = i >> 4, r = i & 15;
        sXT[t][r] = x[((size_t)(r0 + r) * T_LEN + t) * D_DIM + d];
    }
    // ---- h0 = 0 (zero both buffers) ----
    for (int i = tid; i < 2 * M_DIM * HSTR; i += 256)
        ((u16*)sHh)[i] = 0;

    // ---- W fragments (single f16 term): Bh[gate][k-chunk] ----
    h8v Bh[4][2];
    #pragma unroll
    for (int g = 0; g < 4; ++g) {
        const float* Wg = (g == 0 ? Wj : g == 1 ? Wi : g == 2 ? Wf : Wo)
                          + d * (N_DIM * N_DIM);
        #pragma unroll
        for (int c = 0; c < 2; ++c) {
            uint p[4];
            #pragma unroll
            for (int jp = 0; jp < 4; ++jp) {
                float w0 = Wg[(32 * c + quad * 8 + 2 * jp + 0) * N_DIM + n];
                float w1 = Wg[(32 * c + quad * 8 + 2 * jp + 1) * N_DIM + n];
                p[jp] = f2h2(w0, w1);
            }
            Bh[g][c] = pack4h(p[0], p[1], p[2], p[3]);
        }
    }

    // ---- fan-vector B fragment: B[k][col] = f16(fan[k]), col-replicated ->
    //      D[row][col] = sum_k h[row,k]*fan[k] lands in ALL lanes ----
    h8v Ff[2];
    #pragma unroll
    for (int c = 0; c < 2; ++c) {
        uint p[4];
        #pragma unroll
        for (int jp = 0; jp < 4; ++jp) {
            float f0 = Fa[d * N_DIM + 32 * c + quad * 8 + 2 * jp + 0];
            float f1 = Fa[d * N_DIM + 32 * c + quad * 8 + 2 * jp + 1];
            p[jp] = f2h2(f0, f1);
        }
        Ff[c] = pack4h(p[0], p[1], p[2], p[3]);
    }

    const int dn = d * N_DIM + n;
    const float u_j = Uj[dn], u_i = Ui[dn], u_f = Uf[dn], u_o = Uo[dn];
    const float cbj = bj[dn], cbi = bi_[dn], cbf = bf_[dn], cbo = bo[dn];
    const float fab = Fab[d];

    __syncthreads();

    float c_[4] = {0.f, 0.f, 0.f, 0.f};
    float h_[4] = {0.f, 0.f, 0.f, 0.f};
    float ga[4] = {0.f, 0.f, 0.f, 0.f};
    // as init cancels the spurious t=-1 alpha term exactly: at t=0 the
    // A-frags are exactly 0 -> af=0 -> al = exp(tanh(fab)).
    const float al_m1 = __expf(tanh_f(fab));
    float as[4] = {-al_m1, -al_m1, -al_m1, -al_m1};

    #pragma unroll 2
    for (int t = 0; t < T_LEN; ++t) {
        const int wb = t & 1;        // write buffer (h_t)
        const int rb = wb ^ 1;       // read buffer (h_{t-1})

        // ---- A fragments: 2 direct b128 reads, zero unpack ----
        h8v Ah[2];
        #pragma unroll
        for (int c = 0; c < 2; ++c)
            Ah[c] = *(const h8v*)&sHh[rb][col][32 * c + quad * 8];

        // ---- alpha logit for step t-1 via MFMA (2 independent) ----
        f4v af0 = {0.f, 0.f, 0.f, 0.f};
        f4v af1 = {0.f, 0.f, 0.f, 0.f};
        af0 = __builtin_amdgcn_mfma_f32_16x16x32_f16(Ah[0], Ff[0], af0, 0, 0, 0);
        af1 = __builtin_amdgcn_mfma_f32_16x16x32_f16(Ah[1], Ff[1], af1, 0, 0, 0);

        // ---- 8 gate MFMAs: 4 gates x 2 k-chunks ----
        f4v acc[4];
        #pragma unroll
        for (int g = 0; g < 4; ++g) {
            f4v a = {0.f, 0.f, 0.f, 0.f};
            a = __builtin_amdgcn_mfma_f32_16x16x32_f16(Ah[0], Bh[g][0], a, 0, 0, 0);
            a = __builtin_amdgcn_mfma_f32_16x16x32_f16(Ah[1], Bh[g][1], a, 0, 0, 0);
            acc[g] = a;
        }

        // ---- alpha(t-1): independent of the gate chain, uses OLD h_ ----
        #pragma unroll
        for (int r = 0; r < 4; ++r) {
            float tot = af0[r] + af1[r] + fab;
            float al = __expf(tanh_f(tot));
            as[r] += al;
            ga[r] = fmaf(al, h_[r], ga[r]);
        }

        // ---- stage 3: C regs 0..3 = real rows rrow..rrow+3 at n ----
        f4v xr = *(const f4v*)&sXT[t][rrow];
        #pragma unroll
        for (int r = 0; r < 4; ++r) {
            float xv = xr[r];
            float jp = acc[0][r] + fmaf(xv, u_j, cbj);
            float ip = acc[1][r] + fmaf(xv, u_i, cbi);
            float fp = acc[2][r] + fmaf(xv, u_f, cbf);
            float op = acc[3][r] + fmaf(xv, u_o, cbo);
            c_[r] = fmaf(c_[r], sig_f(fp), sig_f(ip) * tanh_f(jp));
            h_[r] = sig_f(op) * tanh_f(c_[r]);
        }

        // ---- write h_t (single f16 plane, rows rrow..rrow+3) ----
        #pragma unroll
        for (int r = 0; r < 4; ++r) {
            union { _Float16 h; u16 s; } xh;
            xh.h = (_Float16)h_[r];
            sHh[wb][rrow + r][n] = xh.s;
        }

        __syncthreads();   // the ONLY barrier: h_t plane visible
    }

    // ---- drain alpha(T-1): h_{T-1} is in buffer (T-1)&1 = 1 ----
    {
        h8v Ah[2];
        #pragma unroll
        for (int c = 0; c < 2; ++c)
            Ah[c] = *(const h8v*)&sHh[1][col][32 * c + quad * 8];
        f4v a0 = {0.f, 0.f, 0.f, 0.f};
        f4v a1 = {0.f, 0.f, 0.f, 0.f};
        a0 = __builtin_amdgcn_mfma_f32_16x16x32_f16(Ah[0], Ff[0], a0, 0, 0, 0);
        a1 = __builtin_amdgcn_mfma_f32_16x16x32_f16(Ah[1], Ff[1], a1, 0, 0, 0);
        #pragma unroll
        for (int r = 0; r < 4; ++r) {
            float tot = a0[r] + a1[r] + fab;
            float al = __expf(tanh_f(tot));
            as[r] += al;
            ga[r] = fmaf(al, h_[r], ga[r]);
        }
    }

    // ---- epilogue: mu, beta per (row, d) ----
    const float pwa = Pw[n],  pwb = Pw[64 + n];
    const float fwa = Fbw[n], fwb = Fbw[64 + n];
    float pm[4], pv[4];
    #pragma unroll
    for (int r = 0; r < 4; ++r) {
        float gn = ga[r] * rcp_f(as[r]);
        pm[r] = fmaf(gn, pwa, h_[r] * pwb);
        pv[r] = fmaf(gn, fwa, h_[r] * fwb);
        pm[r] += __shfl_xor(pm[r], 1); pm[r] += __shfl_xor(pm[r], 2);
        pm[r] += __shfl_xor(pm[r], 4); pm[r] += __shfl_xor(pm[r], 8);
        pv[r] += __shfl_xor(pv[r], 1); pv[r] += __shfl_xor(pv[r], 2);
        pv[r] += __shfl_xor(pv[r], 4); pv[r] += __shfl_xor(pv[r], 8);
    }
    if (col == 0) {
        #pragma unroll
        for (int r = 0; r < 4; ++r) {
            sPS[rrow + r][wg] = pm[r];
            sPV[rrow + r][wg] = pv[r];
        }
    }
    __syncthreads();
    if (tid < R_TILE) {
        int r = tid;
        f4v a  = *(const f4v*)&sPS[r][0];
        f4v b2 = *(const f4v*)&sPV[r][0];
        float mu = a[0] + a[1] + a[2] + a[3] + Pb[0];
        float bt = __expf(tanh_f(b2[0] + b2[1] + b2[2] + b2[3] + Fbb[0]));
        wmu  [(r0 + r) * D_DIM + d] = mu;
        wbeta[(r0 + r) * D_DIM + d] = bt;
    }
}

// beta softmax over d + weighted sum -> out[b]
__global__ void imv_finalize(const float* __restrict__ wmu,
                             const float* __restrict__ wbeta,
                             float* __restrict__ out)
{
    int b = blockIdx.x * 64 + threadIdx.x;
    if (b >= B_ALL) return;
    float s1 = 0.f, s2 = 0.f;
    for (int d = 0; d < D_DIM; ++d) {
        float be = wbeta[b * D_DIM + d];
        s1 = fmaf(be, wmu[b * D_DIM + d], s1);
        s2 += be;
    }
    out[b] = s1 / s2;
}

extern "C" void kernel_launch(void* const* d_in, const int* in_sizes, int n_in,
                              void* d_out, int out_size, void* d_ws, size_t ws_size,
                              hipStream_t stream)
{
    const float* x   = (const float*)d_in[0];
    const float* U_j = (const float*)d_in[1];
    const float* U_i = (const float*)d_in[2];
    const float* U_f = (const float*)d_in[3];
    const float* U_o = (const float*)d_in[4];
    const float* W_j = (const float*)d_in[5];
    const float* W_i = (const float*)d_in[6];
    const float* W_f = (const float*)d_in[7];
    const float* W_o = (const float*)d_in[8];
    const float* b_j = (const float*)d_in[9];
    const float* b_i = (const float*)d_in[10];
    const float* b_f = (const float*)d_in[11];
    const float* b_o = (const float*)d_in[12];
    const float* Fan  = (const float*)d_in[13];
    const float* Fanb = (const float*)d_in[14];
    const float* Fbw  = (const float*)d_in[15];
    const float* Fbb  = (const float*)d_in[16];
    const float* Phw  = (const float*)d_in[17];
    const float* Phb  = (const float*)d_in[18];

    float* wmu   = (float*)d_ws;
    float* wbeta = wmu + B_ALL * D_DIM;

    imv_lstm_scan<<<dim3(256), dim3(256), 0, stream>>>(
        x, U_j, U_i, U_f, U_o, W_j, W_i, W_f, W_o,
        b_j, b_i, b_f, b_o, Fan, Fanb, Fbw, Fbb, Phw, Phb,
        wmu, wbeta);

    imv_finalize<<<dim3(2), dim3(64), 0, stream>>>(wmu, wbeta, (float*)d_out);
}

// Round 14
// 373.773 us; speedup vs baseline: 1.2292x; 1.2292x over previous
//
#include <hip/hip_runtime.h>

#define T_LEN 512
#define D_DIM 32
#define N_DIM 64
#define B_ALL 128
#define R_TILE 8      // real batch rows per block (M=16 MFMA, rows permuted)
#define M_DIM 16      // MFMA M dimension
#define HSTR 72       // ushort row stride for h plane: 16B-aligned, bank-spread

typedef _Float16 h8v __attribute__((ext_vector_type(8)));  // 8 f16 (4 VGPRs)
typedef float f4v __attribute__((ext_vector_type(4)));     // MFMA C/D
typedef float f2v __attribute__((ext_vector_type(2)));
typedef unsigned int uint;
typedef unsigned short u16;

#define L2E 1.4426950408889634f   // log2(e)

__device__ __forceinline__ float rcp_f(float x) {
#if __has_builtin(__builtin_amdgcn_rcpf)
    return __builtin_amdgcn_rcpf(x);
#else
    return 1.0f / x;
#endif
}
__device__ __forceinline__ float ex2(float x) {            // 2^x (v_exp_f32)
#if __has_builtin(__builtin_amdgcn_exp2f)
    return __builtin_amdgcn_exp2f(x);
#else
    return exp2f(x);
#endif
}
__device__ __forceinline__ float tanh_f(float x) {         // epilogue only
    float e = __expf(2.0f * x);
    return 1.0f - 2.0f * rcp_f(e + 1.0f);
}
// prescaled forms: y already multiplied by 2*L2E (tanh) or -L2E (sigmoid)
__device__ __forceinline__ float th_s(float y) {           // tanh from y=2L2E*x
    return fmaf(-2.0f, rcp_f(ex2(y) + 1.0f), 1.0f);
}
__device__ __forceinline__ float sg_s(float y) {           // sig from y=-L2E*x
    return rcp_f(1.0f + ex2(y));
}
__device__ __forceinline__ uint f2h2(float a, float b) {   // pack two f16 (RNE)
    union { _Float16 h[2]; uint u; } x;
    x.h[0] = (_Float16)a; x.h[1] = (_Float16)b;
    return x.u;
}
__device__ __forceinline__ h8v pack4h(uint a, uint b, uint c, uint d_) {
    union { uint u[4]; h8v v; } x;
    x.u[0] = a; x.u[1] = b; x.u[2] = c; x.u[3] = d_;
    return x.v;
}

// R12 structure (best: 357us dispatch): grid 512 (32 d x 16 row-octets) x
// 256 thr (4 waves) -> 2 de-phased blocks/CU; f16 single-plane h; alpha
// via 2 fan-vector MFMAs; 8 gate MFMAs; 1 barrier/step; M-row permutation
// (real row r at M index 4*(r>>1)+(r&1); lane owns rows 2quad..+1 in C
// regs 0,1). R13 (full-M, 1 blk/CU) regressed to 402: redundancy/occupancy
// optimum is HERE (2 blocks, 2x MFMA redundancy).
// R14 delta (VALU trim, last lever per accounting: VALU 1094cy = 65% of
// the 1675cy step, trans-dominated):
//  (1) exp2-prescale: W_j/U_j/fan/fab scaled by 2*log2e, W_ifo/U_ifo by
//      -log2e AT FRAG BUILD -> activations use raw v_exp_f32 (th_s/sg_s),
//      deleting the per-activation scale-mul (10 muls/wave-step) and
//      shortening each trans dep chain by 1. f16(W*S) vs f16(W)*S differs
//      ~1e-5 in preacts -- proven output-invisible (R11/R12).
//  (2) gate MFMAs issue before alpha MFMAs (stage-3 deps retire first).
//  (3) s_setprio(1) around the MFMA cluster (T5: de-phased co-blocks have
//      role diversity, the condition under which setprio pays).
// NOTE: C-fold of x*U+b into MFMA C-in regressed (R5/R6) - keep acc=0.
__global__ void __launch_bounds__(256, 2)
imv_lstm_scan(const float* __restrict__ x,
              const float* __restrict__ Uj, const float* __restrict__ Ui,
              const float* __restrict__ Uf, const float* __restrict__ Uo,
              const float* __restrict__ Wj, const float* __restrict__ Wi,
              const float* __restrict__ Wf, const float* __restrict__ Wo,
              const float* __restrict__ bj, const float* __restrict__ bi_,
              const float* __restrict__ bf_, const float* __restrict__ bo,
              const float* __restrict__ Fa, const float* __restrict__ Fab,
              const float* __restrict__ Fbw, const float* __restrict__ Fbb,
              const float* __restrict__ Pw, const float* __restrict__ Pb,
              float* __restrict__ wmu, float* __restrict__ wbeta)
{
    __shared__ float sXT[T_LEN][R_TILE];     // 16 KB, [t][r]
    __shared__ u16   sHh[2][M_DIM][HSTR];    // 4.5 KB, h f16, [buf][Mrow][k]
    __shared__ float sPS[R_TILE][4];         // epilogue mu partials
    __shared__ float sPV[R_TILE][4];         // epilogue beta partials

    const int tid  = threadIdx.x;
    const int lane = tid & 63;
    const int wg   = tid >> 6;               // 0..3 (n-group)
    const int quad = lane >> 4;              // 0..3
    const int col  = lane & 15;
    const int d    = blockIdx.x & 31;
    const int rt   = blockIdx.x >> 5;        // 0..15
    const int r0   = rt * R_TILE;
    const int n    = wg * 16 + col;          // this lane's n
    const int mrow = quad * 4;               // first M row of lane's 2 rows
    const int rrow = quad * 2;               // first real row of lane's 2

    const float S_T = 2.0f * L2E;            // tanh-gate prescale
    const float S_S = -L2E;                  // sigmoid-gate prescale

    // ---- stage x transposed: sXT[t][r] ----
    for (int i = tid; i < R_TILE * T_LEN; i += 256) {
        int t = i >> 3, r = i & 7;
        sXT[t][r] = x[((size_t)(r0 + r) * T_LEN + t) * D_DIM + d];
    }
    // ---- h0 = 0 (zero both buffers; unwritten M rows stay 0 forever) ----
    for (int i = tid; i < 2 * M_DIM * HSTR; i += 256)
        ((u16*)sHh)[i] = 0;

    // ---- W fragments (single f16 term, PRESCALED): Bh[gate][k-chunk] ----
    h8v Bh[4][2];
    #pragma unroll
    for (int g = 0; g < 4; ++g) {
        const float* Wg = (g == 0 ? Wj : g == 1 ? Wi : g == 2 ? Wf : Wo)
                          + d * (N_DIM * N_DIM);
        const float sc = (g == 0 ? S_T : S_S);
        #pragma unroll
        for (int c = 0; c < 2; ++c) {
            uint p[4];
            #pragma unroll
            for (int jp = 0; jp < 4; ++jp) {
                float w0 = sc * Wg[(32 * c + quad * 8 + 2 * jp + 0) * N_DIM + n];
                float w1 = sc * Wg[(32 * c + quad * 8 + 2 * jp + 1) * N_DIM + n];
                p[jp] = f2h2(w0, w1);
            }
            Bh[g][c] = pack4h(p[0], p[1], p[2], p[3]);
        }
    }

    // ---- fan-vector B fragment (PRESCALED by S_T), col-replicated ----
    h8v Ff[2];
    #pragma unroll
    for (int c = 0; c < 2; ++c) {
        uint p[4];
        #pragma unroll
        for (int jp = 0; jp < 4; ++jp) {
            float f0 = S_T * Fa[d * N_DIM + 32 * c + quad * 8 + 2 * jp + 0];
            float f1 = S_T * Fa[d * N_DIM + 32 * c + quad * 8 + 2 * jp + 1];
            p[jp] = f2h2(f0, f1);
        }
        Ff[c] = pack4h(p[0], p[1], p[2], p[3]);
    }

    const int dn = d * N_DIM + n;
    const float u_j = S_T * Uj[dn], u_i = S_S * Ui[dn];
    const float u_f = S_S * Uf[dn], u_o = S_S * Uo[dn];
    const float cbj = S_T * bj[dn], cbi = S_S * bi_[dn];
    const float cbf = S_S * bf_[dn], cbo = S_S * bo[dn];
    const float fab_s = S_T * Fab[d];

    __syncthreads();

    float c_[2] = {0.f, 0.f};
    float h_[2] = {0.f, 0.f};
    float ga[2] = {0.f, 0.f};
    // as init cancels the spurious t=-1 alpha term exactly: at t=0 the
    // A-frags are exactly 0 -> af=0 -> al = exp(th_s(fab_s)). Computed
    // IDENTICALLY to the in-loop form so the cancellation is bitwise.
    const float al_m1 = __expf(th_s(fab_s));
    float as[2] = {-al_m1, -al_m1};

    #pragma unroll 2
    for (int t = 0; t < T_LEN; ++t) {
        const int wb = t & 1;        // write buffer (h_t)
        const int rb = wb ^ 1;       // read buffer (h_{t-1})

        // ---- A fragments: 2 direct b128 reads, zero unpack ----
        h8v Ah[2];
        #pragma unroll
        for (int c = 0; c < 2; ++c)
            Ah[c] = *(const h8v*)&sHh[rb][col][32 * c + quad * 8];

        // ---- MFMA cluster (setprio-boosted): gates first, alpha after ----
        __builtin_amdgcn_s_setprio(1);
        f4v acc[4];
        #pragma unroll
        for (int g = 0; g < 4; ++g) {
            f4v a = {0.f, 0.f, 0.f, 0.f};
            a = __builtin_amdgcn_mfma_f32_16x16x32_f16(Ah[0], Bh[g][0], a, 0, 0, 0);
            a = __builtin_amdgcn_mfma_f32_16x16x32_f16(Ah[1], Bh[g][1], a, 0, 0, 0);
            acc[g] = a;
        }
        f4v af0 = {0.f, 0.f, 0.f, 0.f};
        f4v af1 = {0.f, 0.f, 0.f, 0.f};
        af0 = __builtin_amdgcn_mfma_f32_16x16x32_f16(Ah[0], Ff[0], af0, 0, 0, 0);
        af1 = __builtin_amdgcn_mfma_f32_16x16x32_f16(Ah[1], Ff[1], af1, 0, 0, 0);
        __builtin_amdgcn_s_setprio(0);

        // ---- alpha(t-1): independent of the gate chain, uses OLD h_ ----
        #pragma unroll
        for (int r = 0; r < 2; ++r) {
            float tot = af0[r] + af1[r] + fab_s;
            float al = __expf(th_s(tot));
            as[r] += al;
            ga[r] = fmaf(al, h_[r], ga[r]);
        }

        // ---- stage 3: C regs 0,1 = real rows rrow, rrow+1 at n ----
        f2v xr = *(const f2v*)&sXT[t][rrow];
        #pragma unroll
        for (int r = 0; r < 2; ++r) {
            float xv = xr[r];
            float jp = acc[0][r] + fmaf(xv, u_j, cbj);   // scaled by S_T
            float ip = acc[1][r] + fmaf(xv, u_i, cbi);   // scaled by S_S
            float fp = acc[2][r] + fmaf(xv, u_f, cbf);
            float op = acc[3][r] + fmaf(xv, u_o, cbo);
            float tj = th_s(jp);
            float si = sg_s(ip);
            float sf = sg_s(fp);
            float so = sg_s(op);
            c_[r] = fmaf(c_[r], sf, si * tj);
            float tc = th_s(S_T * c_[r]);
            h_[r] = so * tc;
        }

        // ---- write h_t (single f16 plane, M rows mrow..mrow+1) ----
        #pragma unroll
        for (int r = 0; r < 2; ++r) {
            union { _Float16 h; u16 s; } xh;
            xh.h = (_Float16)h_[r];
            sHh[wb][mrow + r][n] = xh.s;
        }

        __syncthreads();   // the ONLY barrier: h_t plane visible
    }

    // ---- drain alpha(T-1): h_{T-1} is in buffer (T-1)&1 = 1 ----
    {
        h8v Ah[2];
        #pragma unroll
        for (int c = 0; c < 2; ++c)
            Ah[c] = *(const h8v*)&sHh[1][col][32 * c + quad * 8];
        f4v a0 = {0.f, 0.f, 0.f, 0.f};
        f4v a1 = {0.f, 0.f, 0.f, 0.f};
        a0 = __builtin_amdgcn_mfma_f32_16x16x32_f16(Ah[0], Ff[0], a0, 0, 0, 0);
        a1 = __builtin_amdgcn_mfma_f32_16x16x32_f16(Ah[1], Ff[1], a1, 0, 0, 0);
        #pragma unroll
        for (int r = 0; r < 2; ++r) {
            float tot = a0[r] + a1[r] + fab_s;
            float al = __expf(th_s(tot));
            as[r] += al;
            ga[r] = fmaf(al, h_[r], ga[r]);
        }
    }

    // ---- epilogue: mu, beta per (row, d) ----
    const float pwa = Pw[n],  pwb = Pw[64 + n];
    const float fwa = Fbw[n], fwb = Fbw[64 + n];
    float pm[2], pv[2];
    #pragma unroll
    for (int r = 0; r < 2; ++r) {
        float gn = ga[r] * rcp_f(as[r]);
        pm[r] = fmaf(gn, pwa, h_[r] * pwb);
        pv[r] = fmaf(gn, fwa, h_[r] * fwb);
        pm[r] += __shfl_xor(pm[r], 1); pm[r] += __shfl_xor(pm[r], 2);
        pm[r] += __shfl_xor(pm[r], 4); pm[r] += __shfl_xor(pm[r], 8);
        pv[r] += __shfl_xor(pv[r], 1); pv[r] += __shfl_xor(pv[r], 2);
        pv[r] += __shfl_xor(pv[r], 4); pv[r] += __shfl_xor(pv[r], 8);
    }
    if (col == 0) {
        #pragma unroll
        for (int r = 0; r < 2; ++r) {
            sPS[rrow + r][wg] = pm[r];
            sPV[rrow + r][wg] = pv[r];
        }
    }
    __syncthreads();
    if (tid < R_TILE) {
        int r = tid;
        f4v a  = *(const f4v*)&sPS[r][0];
        f4v b2 = *(const f4v*)&sPV[r][0];
        float mu = a[0] + a[1] + a[2] + a[3] + Pb[0];
        float bt = __expf(tanh_f(b2[0] + b2[1] + b2[2] + b2[3] + Fbb[0]));
        wmu  [(r0 + r) * D_DIM + d] = mu;
        wbeta[(r0 + r) * D_DIM + d] = bt;
    }
}

// beta softmax over d + weighted sum -> out[b]
__global__ void imv_finalize(const float* __restrict__ wmu,
                             const float* __restrict__ wbeta,
                             float* __restrict__ out)
{
    int b = blockIdx.x * 64 + threadIdx.x;
    if (b >= B_ALL) return;
    float s1 = 0.f, s2 = 0.f;
    for (int d = 0; d < D_DIM; ++d) {
        float be = wbeta[b * D_DIM + d];
        s1 = fmaf(be, wmu[b * D_DIM + d], s1);
        s2 += be;
    }
    out[b] = s1 / s2;
}

extern "C" void kernel_launch(void* const* d_in, const int* in_sizes, int n_in,
                              void* d_out, int out_size, void* d_ws, size_t ws_size,
                              hipStream_t stream)
{
    const float* x   = (const float*)d_in[0];
    const float* U_j = (const float*)d_in[1];
    const float* U_i = (const float*)d_in[2];
    const float* U_f = (const float*)d_in[3];
    const float* U_o = (const float*)d_in[4];
    const float* W_j = (const float*)d_in[5];
    const float* W_i = (const float*)d_in[6];
    const float* W_f = (const float*)d_in[7];
    const float* W_o = (const float*)d_in[8];
    const float* b_j = (const float*)d_in[9];
    const float* b_i = (const float*)d_in[10];
    const float* b_f = (const float*)d_in[11];
    const float* b_o = (const float*)d_in[12];
    const float* Fan  = (const float*)d_in[13];
    const float* Fanb = (const float*)d_in[14];
    const float* Fbw  = (const float*)d_in[15];
    const float* Fbb  = (const float*)d_in[16];
    const float* Phw  = (const float*)d_in[17];
    const float* Phb  = (const float*)d_in[18];

    float* wmu   = (float*)d_ws;
    float* wbeta = wmu + B_ALL * D_DIM;

    imv_lstm_scan<<<dim3(512), dim3(256), 0, stream>>>(
        x, U_j, U_i, U_f, U_o, W_j, W_i, W_f, W_o,
        b_j, b_i, b_f, b_o, Fan, Fanb, Fbw, Fbb, Phw, Phb,
        wmu, wbeta);

    imv_finalize<<<dim3(2), dim3(64), 0, stream>>>(wmu, wbeta, (float*)d_out);
}

// Round 15
// 367.378 us; speedup vs baseline: 1.2506x; 1.0174x over previous
//
#include <hip/hip_runtime.h>

#define T_LEN 512
#define D_DIM 32
#define N_DIM 64
#define B_ALL 128
#define R_TILE 8      // real batch rows per block (M=16 MFMA, rows permuted)
#define M_DIM 16      // MFMA M dimension
#define HSTR 72       // ushort row stride for h plane: 16B-aligned, bank-spread

typedef _Float16 h8v __attribute__((ext_vector_type(8)));  // 8 f16 (4 VGPRs)
typedef float f4v __attribute__((ext_vector_type(4)));     // MFMA C/D
typedef float f2v __attribute__((ext_vector_type(2)));
typedef unsigned int uint;
typedef unsigned short u16;

#define L2E 1.4426950408889634f   // log2(e)

__device__ __forceinline__ float rcp_f(float x) {
#if __has_builtin(__builtin_amdgcn_rcpf)
    return __builtin_amdgcn_rcpf(x);
#else
    return 1.0f / x;
#endif
}
__device__ __forceinline__ float ex2(float x) {            // 2^x (v_exp_f32)
#if __has_builtin(__builtin_amdgcn_exp2f)
    return __builtin_amdgcn_exp2f(x);
#else
    return exp2f(x);
#endif
}
__device__ __forceinline__ float tanh_f(float x) {         // epilogue only
    float e = __expf(2.0f * x);
    return 1.0f - 2.0f * rcp_f(e + 1.0f);
}
// prescaled forms: y already multiplied by 2*L2E (tanh) or -L2E (sigmoid)
__device__ __forceinline__ float th_s(float y) {           // tanh from y=2L2E*x
    return fmaf(-2.0f, rcp_f(ex2(y) + 1.0f), 1.0f);
}
__device__ __forceinline__ float sg_s(float y) {           // sig from y=-L2E*x
    return rcp_f(1.0f + ex2(y));
}
// exp(tanh(x)) from y=2L2E*x, L2E folded: ex2(L2E - 2L2E*rcp(ex2(y)+1))
__device__ __forceinline__ float expth_s(float y) {
    return ex2(fmaf(-2.0f * L2E, rcp_f(ex2(y) + 1.0f), L2E));
}
__device__ __forceinline__ uint f2h2(float a, float b) {   // pack two f16 (RNE)
    union { _Float16 h[2]; uint u; } x;
    x.h[0] = (_Float16)a; x.h[1] = (_Float16)b;
    return x.u;
}
__device__ __forceinline__ h8v pack4h(uint a, uint b, uint c, uint d_) {
    union { uint u[4]; h8v v; } x;
    x.u[0] = a; x.u[1] = b; x.u[2] = c; x.u[3] = d_;
    return x.v;
}

// R14 structure (best: 318us dispatch): grid 512 (32 d x 16 row-octets) x
// 256 thr (4 waves) -> 2 de-phased blocks/CU; f16 single-plane h; exp2-
// prescaled gates (W_j/U_j/fan/fab by 2log2e, W_ifo/U_ifo by -log2e at
// frag build); 8 gate + 2 alpha MFMAs, setprio(1) around the cluster;
// 1 barrier/step; M-row permutation (real row r at M index 4*(r>>1)+(r&1)).
// R15 delta (stall trim, in-order-issue fix): the alpha-consume block sat
// between the MFMA cluster and stage-3; its first op needs af0 (result of
// the LAST MFMAs), so issue stalled there and ~22 alpha ops (6 trans)
// issued before stage-3 could start -- pure critical-path padding, since
// alpha only needs af + OLD h. Moved: save hp=h_(t-1) in 2 temps, run
// stage-3 + h-write first, consume alpha AFTER the ds_writes issue (alpha
// VALU hides under the write drain / co-block phase). Riders: xr LDS read
// hoisted before the MFMA cluster (latency under MFMA); alpha exp folds
// L2E into the fma (expth_s, -1 mul). Same values, reordered -> absmax
// stays ~5.96e-08.
// NOTE: C-fold of x*U+b into MFMA C-in regressed (R5/R6) - keep acc=0.
__global__ void __launch_bounds__(256, 2)
imv_lstm_scan(const float* __restrict__ x,
              const float* __restrict__ Uj, const float* __restrict__ Ui,
              const float* __restrict__ Uf, const float* __restrict__ Uo,
              const float* __restrict__ Wj, const float* __restrict__ Wi,
              const float* __restrict__ Wf, const float* __restrict__ Wo,
              const float* __restrict__ bj, const float* __restrict__ bi_,
              const float* __restrict__ bf_, const float* __restrict__ bo,
              const float* __restrict__ Fa, const float* __restrict__ Fab,
              const float* __restrict__ Fbw, const float* __restrict__ Fbb,
              const float* __restrict__ Pw, const float* __restrict__ Pb,
              float* __restrict__ wmu, float* __restrict__ wbeta)
{
    __shared__ float sXT[T_LEN][R_TILE];     // 16 KB, [t][r]
    __shared__ u16   sHh[2][M_DIM][HSTR];    // 4.5 KB, h f16, [buf][Mrow][k]
    __shared__ float sPS[R_TILE][4];         // epilogue mu partials
    __shared__ float sPV[R_TILE][4];         // epilogue beta partials

    const int tid  = threadIdx.x;
    const int lane = tid & 63;
    const int wg   = tid >> 6;               // 0..3 (n-group)
    const int quad = lane >> 4;              // 0..3
    const int col  = lane & 15;
    const int d    = blockIdx.x & 31;
    const int rt   = blockIdx.x >> 5;        // 0..15
    const int r0   = rt * R_TILE;
    const int n    = wg * 16 + col;          // this lane's n
    const int mrow = quad * 4;               // first M row of lane's 2 rows
    const int rrow = quad * 2;               // first real row of lane's 2

    const float S_T = 2.0f * L2E;            // tanh-gate prescale
    const float S_S = -L2E;                  // sigmoid-gate prescale

    // ---- stage x transposed: sXT[t][r] ----
    for (int i = tid; i < R_TILE * T_LEN; i += 256) {
        int t = i >> 3, r = i & 7;
        sXT[t][r] = x[((size_t)(r0 + r) * T_LEN + t) * D_DIM + d];
    }
    // ---- h0 = 0 (zero both buffers; unwritten M rows stay 0 forever) ----
    for (int i = tid; i < 2 * M_DIM * HSTR; i += 256)
        ((u16*)sHh)[i] = 0;

    // ---- W fragments (single f16 term, PRESCALED): Bh[gate][k-chunk] ----
    h8v Bh[4][2];
    #pragma unroll
    for (int g = 0; g < 4; ++g) {
        const float* Wg = (g == 0 ? Wj : g == 1 ? Wi : g == 2 ? Wf : Wo)
                          + d * (N_DIM * N_DIM);
        const float sc = (g == 0 ? S_T : S_S);
        #pragma unroll
        for (int c = 0; c < 2; ++c) {
            uint p[4];
            #pragma unroll
            for (int jp = 0; jp < 4; ++jp) {
                float w0 = sc * Wg[(32 * c + quad * 8 + 2 * jp + 0) * N_DIM + n];
                float w1 = sc * Wg[(32 * c + quad * 8 + 2 * jp + 1) * N_DIM + n];
                p[jp] = f2h2(w0, w1);
            }
            Bh[g][c] = pack4h(p[0], p[1], p[2], p[3]);
        }
    }

    // ---- fan-vector B fragment (PRESCALED by S_T), col-replicated ----
    h8v Ff[2];
    #pragma unroll
    for (int c = 0; c < 2; ++c) {
        uint p[4];
        #pragma unroll
        for (int jp = 0; jp < 4; ++jp) {
            float f0 = S_T * Fa[d * N_DIM + 32 * c + quad * 8 + 2 * jp + 0];
            float f1 = S_T * Fa[d * N_DIM + 32 * c + quad * 8 + 2 * jp + 1];
            p[jp] = f2h2(f0, f1);
        }
        Ff[c] = pack4h(p[0], p[1], p[2], p[3]);
    }

    const int dn = d * N_DIM + n;
    const float u_j = S_T * Uj[dn], u_i = S_S * Ui[dn];
    const float u_f = S_S * Uf[dn], u_o = S_S * Uo[dn];
    const float cbj = S_T * bj[dn], cbi = S_S * bi_[dn];
    const float cbf = S_S * bf_[dn], cbo = S_S * bo[dn];
    const float fab_s = S_T * Fab[d];

    __syncthreads();

    float c_[2] = {0.f, 0.f};
    float h_[2] = {0.f, 0.f};
    float ga[2] = {0.f, 0.f};
    // as init cancels the spurious t=-1 alpha term exactly: at t=0 the
    // A-frags are exactly 0 -> af=0 -> al = expth_s(fab_s). Computed
    // IDENTICALLY to the in-loop form so the cancellation is bitwise.
    const float al_m1 = expth_s(fab_s);
    float as[2] = {-al_m1, -al_m1};

    #pragma unroll 2
    for (int t = 0; t < T_LEN; ++t) {
        const int wb = t & 1;        // write buffer (h_t)
        const int rb = wb ^ 1;       // read buffer (h_{t-1})

        // ---- A fragments + x row: issue all LDS reads up front ----
        h8v Ah[2];
        #pragma unroll
        for (int c = 0; c < 2; ++c)
            Ah[c] = *(const h8v*)&sHh[rb][col][32 * c + quad * 8];
        f2v xr = *(const f2v*)&sXT[t][rrow];

        // ---- MFMA cluster (setprio-boosted): gates first, alpha after ----
        __builtin_amdgcn_s_setprio(1);
        f4v acc[4];
        #pragma unroll
        for (int g = 0; g < 4; ++g) {
            f4v a = {0.f, 0.f, 0.f, 0.f};
            a = __builtin_amdgcn_mfma_f32_16x16x32_f16(Ah[0], Bh[g][0], a, 0, 0, 0);
            a = __builtin_amdgcn_mfma_f32_16x16x32_f16(Ah[1], Bh[g][1], a, 0, 0, 0);
            acc[g] = a;
        }
        f4v af0 = {0.f, 0.f, 0.f, 0.f};
        f4v af1 = {0.f, 0.f, 0.f, 0.f};
        af0 = __builtin_amdgcn_mfma_f32_16x16x32_f16(Ah[0], Ff[0], af0, 0, 0, 0);
        af1 = __builtin_amdgcn_mfma_f32_16x16x32_f16(Ah[1], Ff[1], af1, 0, 0, 0);
        __builtin_amdgcn_s_setprio(0);

        // ---- save h_{t-1} for the deferred alpha consume ----
        const float hp0 = h_[0], hp1 = h_[1];

        // ---- stage 3 FIRST (acc ready earliest): rows rrow, rrow+1 ----
        #pragma unroll
        for (int r = 0; r < 2; ++r) {
            float xv = xr[r];
            float jp = acc[0][r] + fmaf(xv, u_j, cbj);   // scaled by S_T
            float ip = acc[1][r] + fmaf(xv, u_i, cbi);   // scaled by S_S
            float fp = acc[2][r] + fmaf(xv, u_f, cbf);
            float op = acc[3][r] + fmaf(xv, u_o, cbo);
            float tj = th_s(jp);
            float si = sg_s(ip);
            float sf = sg_s(fp);
            float so = sg_s(op);
            c_[r] = fmaf(c_[r], sf, si * tj);
            float tc = th_s(S_T * c_[r]);
            h_[r] = so * tc;
        }

        // ---- h-write issues next (ds_write drains under alpha VALU) ----
        #pragma unroll
        for (int r = 0; r < 2; ++r) {
            union { _Float16 h; u16 s; } xh;
            xh.h = (_Float16)h_[r];
            sHh[wb][mrow + r][n] = xh.s;
        }

        // ---- alpha(t-1) LAST: off the critical path; uses af + hp ----
        {
            float a0 = expth_s(af0[0] + af1[0] + fab_s);
            float a1 = expth_s(af0[1] + af1[1] + fab_s);
            as[0] += a0;  ga[0] = fmaf(a0, hp0, ga[0]);
            as[1] += a1;  ga[1] = fmaf(a1, hp1, ga[1]);
        }

        __syncthreads();   // the ONLY barrier: h_t plane visible
    }

    // ---- drain alpha(T-1): h_{T-1} is in buffer (T-1)&1 = 1 ----
    {
        h8v Ah[2];
        #pragma unroll
        for (int c = 0; c < 2; ++c)
            Ah[c] = *(const h8v*)&sHh[1][col][32 * c + quad * 8];
        f4v a0 = {0.f, 0.f, 0.f, 0.f};
        f4v a1 = {0.f, 0.f, 0.f, 0.f};
        a0 = __builtin_amdgcn_mfma_f32_16x16x32_f16(Ah[0], Ff[0], a0, 0, 0, 0);
        a1 = __builtin_amdgcn_mfma_f32_16x16x32_f16(Ah[1], Ff[1], a1, 0, 0, 0);
        #pragma unroll
        for (int r = 0; r < 2; ++r) {
            float al = expth_s(a0[r] + a1[r] + fab_s);
            as[r] += al;
            ga[r] = fmaf(al, h_[r], ga[r]);
        }
    }

    // ---- epilogue: mu, beta per (row, d) ----
    const float pwa = Pw[n],  pwb = Pw[64 + n];
    const float fwa = Fbw[n], fwb = Fbw[64 + n];
    float pm[2], pv[2];
    #pragma unroll
    for (int r = 0; r < 2; ++r) {
        float gn = ga[r] * rcp_f(as[r]);
        pm[r] = fmaf(gn, pwa, h_[r] * pwb);
        pv[r] = fmaf(gn, fwa, h_[r] * fwb);
        pm[r] += __shfl_xor(pm[r], 1); pm[r] += __shfl_xor(pm[r], 2);
        pm[r] += __shfl_xor(pm[r], 4); pm[r] += __shfl_xor(pm[r], 8);
        pv[r] += __shfl_xor(pv[r], 1); pv[r] += __shfl_xor(pv[r], 2);
        pv[r] += __shfl_xor(pv[r], 4); pv[r] += __shfl_xor(pv[r], 8);
    }
    if (col == 0) {
        #pragma unroll
        for (int r = 0; r < 2; ++r) {
            sPS[rrow + r][wg] = pm[r];
            sPV[rrow + r][wg] = pv[r];
        }
    }
    __syncthreads();
    if (tid < R_TILE) {
        int r = tid;
        f4v a  = *(const f4v*)&sPS[r][0];
        f4v b2 = *(const f4v*)&sPV[r][0];
        float mu = a[0] + a[1] + a[2] + a[3] + Pb[0];
        float bt = __expf(tanh_f(b2[0] + b2[1] + b2[2] + b2[3] + Fbb[0]));
        wmu  [(r0 + r) * D_DIM + d] = mu;
        wbeta[(r0 + r) * D_DIM + d] = bt;
    }
}

// beta softmax over d + weighted sum -> out[b]
__global__ void imv_finalize(const float* __restrict__ wmu,
                             const float* __restrict__ wbeta,
                             float* __restrict__ out)
{
    int b = blockIdx.x * 64 + threadIdx.x;
    if (b >= B_ALL) return;
    float s1 = 0.f, s2 = 0.f;
    for (int d = 0; d < D_DIM; ++d) {
        float be = wbeta[b * D_DIM + d];
        s1 = fmaf(be, wmu[b * D_DIM + d], s1);
        s2 += be;
    }
    out[b] = s1 / s2;
}

extern "C" void kernel_launch(void* const* d_in, const int* in_sizes, int n_in,
                              void* d_out, int out_size, void* d_ws, size_t ws_size,
                              hipStream_t stream)
{
    const float* x   = (const float*)d_in[0];
    const float* U_j = (const float*)d_in[1];
    const float* U_i = (const float*)d_in[2];
    const float* U_f = (const float*)d_in[3];
    const float* U_o = (const float*)d_in[4];
    const float* W_j = (const float*)d_in[5];
    const float* W_i = (const float*)d_in[6];
    const float* W_f = (const float*)d_in[7];
    const float* W_o = (const float*)d_in[8];
    const float* b_j = (const float*)d_in[9];
    const float* b_i = (const float*)d_in[10];
    const float* b_f = (const float*)d_in[11];
    const float* b_o = (const float*)d_in[12];
    const float* Fan  = (const float*)d_in[13];
    const float* Fanb = (const float*)d_in[14];
    const float* Fbw  = (const float*)d_in[15];
    const float* Fbb  = (const float*)d_in[16];
    const float* Phw  = (const float*)d_in[17];
    const float* Phb  = (const float*)d_in[18];

    float* wmu   = (float*)d_ws;
    float* wbeta = wmu + B_ALL * D_DIM;

    imv_lstm_scan<<<dim3(512), dim3(256), 0, stream>>>(
        x, U_j, U_i, U_f, U_o, W_j, W_i, W_f, W_o,
        b_j, b_i, b_f, b_o, Fan, Fanb, Fbw, Fbb, Phw, Phb,
        wmu, wbeta);

    imv_finalize<<<dim3(2), dim3(64), 0, stream>>>(wmu, wbeta, (float*)d_out);
}

// Round 16
// 364.594 us; speedup vs baseline: 1.2602x; 1.0076x over previous
//
#include <hip/hip_runtime.h>

#define T_LEN 512
#define D_DIM 32
#define N_DIM 64
#define B_ALL 128
#define R_TILE 8      // real batch rows per block (M=16 MFMA, rows permuted)
#define M_DIM 16      // MFMA M dimension
#define HSTR 72       // ushort row stride for h plane: 16B-aligned, bank-spread

typedef _Float16 h8v __attribute__((ext_vector_type(8)));  // 8 f16 (4 VGPRs)
typedef float f4v __attribute__((ext_vector_type(4)));     // MFMA C/D
typedef float f2v __attribute__((ext_vector_type(2)));
typedef unsigned int uint;
typedef unsigned short u16;

#define L2E 1.4426950408889634f   // log2(e)

__device__ __forceinline__ float rcp_f(float x) {
#if __has_builtin(__builtin_amdgcn_rcpf)
    return __builtin_amdgcn_rcpf(x);
#else
    return 1.0f / x;
#endif
}
__device__ __forceinline__ float ex2(float x) {            // 2^x (v_exp_f32)
#if __has_builtin(__builtin_amdgcn_exp2f)
    return __builtin_amdgcn_exp2f(x);
#else
    return exp2f(x);
#endif
}
__device__ __forceinline__ float tanh_f(float x) {         // epilogue only
    float e = __expf(2.0f * x);
    return 1.0f - 2.0f * rcp_f(e + 1.0f);
}
// prescaled forms: y already multiplied by 2*L2E (tanh) or -L2E (sigmoid)
__device__ __forceinline__ float th_s(float y) {           // tanh from y=2L2E*x
    return fmaf(-2.0f, rcp_f(ex2(y) + 1.0f), 1.0f);
}
__device__ __forceinline__ float sg_s(float y) {           // sig from y=-L2E*x
    return rcp_f(1.0f + ex2(y));
}
// exp(tanh(x)) from y=2L2E*x, L2E folded: ex2(L2E - 2L2E*rcp(ex2(y)+1))
__device__ __forceinline__ float expth_s(float y) {
    return ex2(fmaf(-2.0f * L2E, rcp_f(ex2(y) + 1.0f), L2E));
}
__device__ __forceinline__ uint f2h2(float a, float b) {   // pack two f16 (RNE)
    union { _Float16 h[2]; uint u; } x;
    x.h[0] = (_Float16)a; x.h[1] = (_Float16)b;
    return x.u;
}
__device__ __forceinline__ h8v pack4h(uint a, uint b, uint c, uint d_) {
    union { uint u[4]; h8v v; } x;
    x.u[0] = a; x.u[1] = b; x.u[2] = c; x.u[3] = d_;
    return x.v;
}

// R15 structure (best: 311us dispatch): grid 512 (32 d x 16 row-octets) x
// 256 thr (4 waves) -> 2 de-phased blocks/CU; f16 single-plane h; exp2-
// prescaled gates; 8 gate + 2 alpha MFMAs, setprio(1) around the cluster;
// alpha consumed AFTER h-write (off critical path); xr hoisted with the
// A-frag reads; 1 barrier/step; M-row permutation (real row r at M index
// 4*(r>>1)+(r&1); lane owns rows 2quad..+1 in C regs 0,1).
// R16 delta (VALU-issue trim): C-IN FOLDS.
//  (1) gate MFMA C-in regs 0,1 = fma(xr, u_g, cb_g) (regs 2,3 = 0) ->
//      stage-3 reads acc directly; saves 8 adds + 8 zero-movs/wave-step.
//      R5/R6's regression on this fold came from the un-hoisted sXT read
//      landing on the MFMA-start path; xr now issues WITH the A-frag
//      loads (same lgkmcnt wait), so the dependency adds ~0 latency.
//  (2) alpha MFMA af0 C-in = fab_s broadcast -> drops +fab_s add; t=-1
//      cancellation stays bitwise (A=0 at t=0 passes C through ->
//      expth_s(fab_s) == al_m1 exactly).
__global__ void __launch_bounds__(256, 2)
imv_lstm_scan(const float* __restrict__ x,
              const float* __restrict__ Uj, const float* __restrict__ Ui,
              const float* __restrict__ Uf, const float* __restrict__ Uo,
              const float* __restrict__ Wj, const float* __restrict__ Wi,
              const float* __restrict__ Wf, const float* __restrict__ Wo,
              const float* __restrict__ bj, const float* __restrict__ bi_,
              const float* __restrict__ bf_, const float* __restrict__ bo,
              const float* __restrict__ Fa, const float* __restrict__ Fab,
              const float* __restrict__ Fbw, const float* __restrict__ Fbb,
              const float* __restrict__ Pw, const float* __restrict__ Pb,
              float* __restrict__ wmu, float* __restrict__ wbeta)
{
    __shared__ float sXT[T_LEN][R_TILE];     // 16 KB, [t][r]
    __shared__ u16   sHh[2][M_DIM][HSTR];    // 4.5 KB, h f16, [buf][Mrow][k]
    __shared__ float sPS[R_TILE][4];         // epilogue mu partials
    __shared__ float sPV[R_TILE][4];         // epilogue beta partials

    const int tid  = threadIdx.x;
    const int lane = tid & 63;
    const int wg   = tid >> 6;               // 0..3 (n-group)
    const int quad = lane >> 4;              // 0..3
    const int col  = lane & 15;
    const int d    = blockIdx.x & 31;
    const int rt   = blockIdx.x >> 5;        // 0..15
    const int r0   = rt * R_TILE;
    const int n    = wg * 16 + col;          // this lane's n
    const int mrow = quad * 4;               // first M row of lane's 2 rows
    const int rrow = quad * 2;               // first real row of lane's 2

    const float S_T = 2.0f * L2E;            // tanh-gate prescale
    const float S_S = -L2E;                  // sigmoid-gate prescale

    // ---- stage x transposed: sXT[t][r] ----
    for (int i = tid; i < R_TILE * T_LEN; i += 256) {
        int t = i >> 3, r = i & 7;
        sXT[t][r] = x[((size_t)(r0 + r) * T_LEN + t) * D_DIM + d];
    }
    // ---- h0 = 0 (zero both buffers; unwritten M rows stay 0 forever) ----
    for (int i = tid; i < 2 * M_DIM * HSTR; i += 256)
        ((u16*)sHh)[i] = 0;

    // ---- W fragments (single f16 term, PRESCALED): Bh[gate][k-chunk] ----
    h8v Bh[4][2];
    #pragma unroll
    for (int g = 0; g < 4; ++g) {
        const float* Wg = (g == 0 ? Wj : g == 1 ? Wi : g == 2 ? Wf : Wo)
                          + d * (N_DIM * N_DIM);
        const float sc = (g == 0 ? S_T : S_S);
        #pragma unroll
        for (int c = 0; c < 2; ++c) {
            uint p[4];
            #pragma unroll
            for (int jp = 0; jp < 4; ++jp) {
                float w0 = sc * Wg[(32 * c + quad * 8 + 2 * jp + 0) * N_DIM + n];
                float w1 = sc * Wg[(32 * c + quad * 8 + 2 * jp + 1) * N_DIM + n];
                p[jp] = f2h2(w0, w1);
            }
            Bh[g][c] = pack4h(p[0], p[1], p[2], p[3]);
        }
    }

    // ---- fan-vector B fragment (PRESCALED by S_T), col-replicated ----
    h8v Ff[2];
    #pragma unroll
    for (int c = 0; c < 2; ++c) {
        uint p[4];
        #pragma unroll
        for (int jp = 0; jp < 4; ++jp) {
            float f0 = S_T * Fa[d * N_DIM + 32 * c + quad * 8 + 2 * jp + 0];
            float f1 = S_T * Fa[d * N_DIM + 32 * c + quad * 8 + 2 * jp + 1];
            p[jp] = f2h2(f0, f1);
        }
        Ff[c] = pack4h(p[0], p[1], p[2], p[3]);
    }

    const int dn = d * N_DIM + n;
    const float u_j = S_T * Uj[dn], u_i = S_S * Ui[dn];
    const float u_f = S_S * Uf[dn], u_o = S_S * Uo[dn];
    const float cbj = S_T * bj[dn], cbi = S_S * bi_[dn];
    const float cbf = S_S * bf_[dn], cbo = S_S * bo[dn];
    const float fab_s = S_T * Fab[d];

    __syncthreads();

    float c_[2] = {0.f, 0.f};
    float h_[2] = {0.f, 0.f};
    float ga[2] = {0.f, 0.f};
    // as init cancels the spurious t=-1 alpha term exactly: at t=0 the
    // A-frags are 0, so the alpha MFMAs pass C straight through ->
    // tot = fab_s -> al = expth_s(fab_s) == al_m1, bitwise.
    const float al_m1 = expth_s(fab_s);
    float as[2] = {-al_m1, -al_m1};

    #pragma unroll 2
    for (int t = 0; t < T_LEN; ++t) {
        const int wb = t & 1;        // write buffer (h_t)
        const int rb = wb ^ 1;       // read buffer (h_{t-1})

        // ---- A fragments + x row: issue all LDS reads up front ----
        h8v Ah[2];
        #pragma unroll
        for (int c = 0; c < 2; ++c)
            Ah[c] = *(const h8v*)&sHh[rb][col][32 * c + quad * 8];
        f2v xr = *(const f2v*)&sXT[t][rrow];

        // ---- MFMA cluster (setprio-boosted): gates first, alpha after.
        //      C-in carries x*U+b (regs 0,1) / fab_s (alpha af0). ----
        __builtin_amdgcn_s_setprio(1);
        f4v acc[4];
        #pragma unroll
        for (int g = 0; g < 4; ++g) {
            const float ug = (g == 0 ? u_j : g == 1 ? u_i : g == 2 ? u_f : u_o);
            const float cg = (g == 0 ? cbj : g == 1 ? cbi : g == 2 ? cbf : cbo);
            f4v a;
            a[0] = fmaf(xr[0], ug, cg);
            a[1] = fmaf(xr[1], ug, cg);
            a[2] = 0.f; a[3] = 0.f;
            a = __builtin_amdgcn_mfma_f32_16x16x32_f16(Ah[0], Bh[g][0], a, 0, 0, 0);
            a = __builtin_amdgcn_mfma_f32_16x16x32_f16(Ah[1], Bh[g][1], a, 0, 0, 0);
            acc[g] = a;
        }
        f4v af0 = {fab_s, fab_s, fab_s, fab_s};
        f4v af1 = {0.f, 0.f, 0.f, 0.f};
        af0 = __builtin_amdgcn_mfma_f32_16x16x32_f16(Ah[0], Ff[0], af0, 0, 0, 0);
        af1 = __builtin_amdgcn_mfma_f32_16x16x32_f16(Ah[1], Ff[1], af1, 0, 0, 0);
        __builtin_amdgcn_s_setprio(0);

        // ---- save h_{t-1} for the deferred alpha consume ----
        const float hp0 = h_[0], hp1 = h_[1];

        // ---- stage 3 FIRST (acc ready earliest): rows rrow, rrow+1 ----
        #pragma unroll
        for (int r = 0; r < 2; ++r) {
            float tj = th_s(acc[0][r]);
            float si = sg_s(acc[1][r]);
            float sf = sg_s(acc[2][r]);
            float so = sg_s(acc[3][r]);
            c_[r] = fmaf(c_[r], sf, si * tj);
            float tc = th_s(S_T * c_[r]);
            h_[r] = so * tc;
        }

        // ---- h-write issues next (ds_write drains under alpha VALU) ----
        #pragma unroll
        for (int r = 0; r < 2; ++r) {
            union { _Float16 h; u16 s; } xh;
            xh.h = (_Float16)h_[r];
            sHh[wb][mrow + r][n] = xh.s;
        }

        // ---- alpha(t-1) LAST: off the critical path; uses af + hp ----
        {
            float a0 = expth_s(af0[0] + af1[0]);
            float a1 = expth_s(af0[1] + af1[1]);
            as[0] += a0;  ga[0] = fmaf(a0, hp0, ga[0]);
            as[1] += a1;  ga[1] = fmaf(a1, hp1, ga[1]);
        }

        __syncthreads();   // the ONLY barrier: h_t plane visible
    }

    // ---- drain alpha(T-1): h_{T-1} is in buffer (T-1)&1 = 1 ----
    {
        h8v Ah[2];
        #pragma unroll
        for (int c = 0; c < 2; ++c)
            Ah[c] = *(const h8v*)&sHh[1][col][32 * c + quad * 8];
        f4v a0 = {fab_s, fab_s, fab_s, fab_s};
        f4v a1 = {0.f, 0.f, 0.f, 0.f};
        a0 = __builtin_amdgcn_mfma_f32_16x16x32_f16(Ah[0], Ff[0], a0, 0, 0, 0);
        a1 = __builtin_amdgcn_mfma_f32_16x16x32_f16(Ah[1], Ff[1], a1, 0, 0, 0);
        #pragma unroll
        for (int r = 0; r < 2; ++r) {
            float al = expth_s(a0[r] + a1[r]);
            as[r] += al;
            ga[r] = fmaf(al, h_[r], ga[r]);
        }
    }

    // ---- epilogue: mu, beta per (row, d) ----
    const float pwa = Pw[n],  pwb = Pw[64 + n];
    const float fwa = Fbw[n], fwb = Fbw[64 + n];
    float pm[2], pv[2];
    #pragma unroll
    for (int r = 0; r < 2; ++r) {
        float gn = ga[r] * rcp_f(as[r]);
        pm[r] = fmaf(gn, pwa, h_[r] * pwb);
        pv[r] = fmaf(gn, fwa, h_[r] * fwb);
        pm[r] += __shfl_xor(pm[r], 1); pm[r] += __shfl_xor(pm[r], 2);
        pm[r] += __shfl_xor(pm[r], 4); pm[r] += __shfl_xor(pm[r], 8);
        pv[r] += __shfl_xor(pv[r], 1); pv[r] += __shfl_xor(pv[r], 2);
        pv[r] += __shfl_xor(pv[r], 4); pv[r] += __shfl_xor(pv[r], 8);
    }
    if (col == 0) {
        #pragma unroll
        for (int r = 0; r < 2; ++r) {
            sPS[rrow + r][wg] = pm[r];
            sPV[rrow + r][wg] = pv[r];
        }
    }
    __syncthreads();
    if (tid < R_TILE) {
        int r = tid;
        f4v a  = *(const f4v*)&sPS[r][0];
        f4v b2 = *(const f4v*)&sPV[r][0];
        float mu = a[0] + a[1] + a[2] + a[3] + Pb[0];
        float bt = __expf(tanh_f(b2[0] + b2[1] + b2[2] + b2[3] + Fbb[0]));
        wmu  [(r0 + r) * D_DIM + d] = mu;
        wbeta[(r0 + r) * D_DIM + d] = bt;
    }
}

// beta softmax over d + weighted sum -> out[b]
__global__ void imv_finalize(const float* __restrict__ wmu,
                             const float* __restrict__ wbeta,
                             float* __restrict__ out)
{
    int b = blockIdx.x * 64 + threadIdx.x;
    if (b >= B_ALL) return;
    float s1 = 0.f, s2 = 0.f;
    for (int d = 0; d < D_DIM; ++d) {
        float be = wbeta[b * D_DIM + d];
        s1 = fmaf(be, wmu[b * D_DIM + d], s1);
        s2 += be;
    }
    out[b] = s1 / s2;
}

extern "C" void kernel_launch(void* const* d_in, const int* in_sizes, int n_in,
                              void* d_out, int out_size, void* d_ws, size_t ws_size,
                              hipStream_t stream)
{
    const float* x   = (const float*)d_in[0];
    const float* U_j = (const float*)d_in[1];
    const float* U_i = (const float*)d_in[2];
    const float* U_f = (const float*)d_in[3];
    const float* U_o = (const float*)d_in[4];
    const float* W_j = (const float*)d_in[5];
    const float* W_i = (const float*)d_in[6];
    const float* W_f = (const float*)d_in[7];
    const float* W_o = (const float*)d_in[8];
    const float* b_j = (const float*)d_in[9];
    const float* b_i = (const float*)d_in[10];
    const float* b_f = (const float*)d_in[11];
    const float* b_o = (const float*)d_in[12];
    const float* Fan  = (const float*)d_in[13];
    const float* Fanb = (const float*)d_in[14];
    const float* Fbw  = (const float*)d_in[15];
    const float* Fbb  = (const float*)d_in[16];
    const float* Phw  = (const float*)d_in[17];
    const float* Phb  = (const float*)d_in[18];

    float* wmu   = (float*)d_ws;
    float* wbeta = wmu + B_ALL * D_DIM;

    imv_lstm_scan<<<dim3(512), dim3(256), 0, stream>>>(
        x, U_j, U_i, U_f, U_o, W_j, W_i, W_f, W_o,
        b_j, b_i, b_f, b_o, Fan, Fanb, Fbw, Fbb, Phw, Phb,
        wmu, wbeta);

    imv_finalize<<<dim3(2), dim3(64), 0, stream>>>(wmu, wbeta, (float*)d_out);
}